// Round 7
// baseline (954.823 us; speedup 1.0000x reference)
//
#include <hip/hip_runtime.h>

typedef __bf16 bf16;
typedef __bf16 bf16x8 __attribute__((ext_vector_type(8)));
typedef float f32x4 __attribute__((ext_vector_type(4)));

#define B_ 2
#define S_ 2048
#define D_ 512
#define H_ 8

// fp32 -> bf16 hi + bf16 lo residual (split precision)
__global__ __launch_bounds__(256) void split_f32(const float* __restrict__ src,
                                                 bf16* __restrict__ hi, bf16* __restrict__ lo,
                                                 long n) {
  long i = (long)blockIdx.x * 256 + threadIdx.x;
  if (i >= n) return;
  float v = src[i];
  bf16 h = (bf16)v;
  hi[i] = h;
  lo[i] = (bf16)(v - (float)h);
}

// [z][R][C] fp32 -> [z][C][R] bf16 hi (+ optional lo residual plane)
__global__ __launch_bounds__(256) void transpose_f32(const float* __restrict__ src,
                                                     bf16* __restrict__ hi, bf16* __restrict__ lo,
                                                     int R, int C) {
  __shared__ float t[32][33];
  size_t zoff = (size_t)blockIdx.z * R * C;
  const float* s = src + zoff;
  int tx = threadIdx.x;  // 0..31
  int ty = threadIdx.y;  // 0..7
  int c0 = blockIdx.x * 32, r0 = blockIdx.y * 32;
#pragma unroll
  for (int i = 0; i < 4; ++i)
    t[ty + i * 8][tx] = s[(size_t)(r0 + ty + i * 8) * C + c0 + tx];
  __syncthreads();
#pragma unroll
  for (int i = 0; i < 4; ++i) {
    float v = t[tx][ty + i * 8];
    size_t o = zoff + (size_t)(c0 + ty + i * 8) * R + r0 + tx;
    bf16 h = (bf16)v;
    hi[o] = h;
    if (lo) lo[o] = (bf16)(v - (float)h);
  }
}

struct GemmArgs {
  const bf16 *A, *Alo, *Bm, *Blo;
  void* C; bf16* Clo;
  const float* bias;
  int K, lda, ldb, ldc;
  unsigned long long sA, sB, sC, sbias;  // per-blockIdx.z strides (elements)
};

// NT GEMM: C[m][n] = sum_k A[m][k]*B[n][k]. BIAS: 0=none,1=bias[n],2=bias[m].
// SIN: A,B have lo residual planes -> 3-term split MFMA (near-fp32 product).
// SOUT: emit bf16 hi plane to C and bf16 residual plane to Clo.
template <typename OutT, int BIAS, bool SIN, bool SOUT>
__global__ __launch_bounds__(256) void gemm_nt(GemmArgs p) {
  long z = blockIdx.z;
  const bf16* A  = p.A  + z * p.sA;
  const bf16* Bm = p.Bm + z * p.sB;
  const bf16* Al = SIN ? (p.Alo + z * p.sA) : nullptr;
  const bf16* Bl = SIN ? (p.Blo + z * p.sB) : nullptr;
  OutT* C = (OutT*)p.C + z * p.sC;
  bf16* Cl = SOUT ? (p.Clo + z * p.sC) : nullptr;
  const float* bias = BIAS ? (p.bias + z * p.sbias) : nullptr;

  extern __shared__ bf16 sm[];
  bf16* lA  = sm;
  bf16* lB  = sm + 4096;
  bf16* lAl = sm + 8192;
  bf16* lBl = sm + 12288;

  int tid = threadIdx.x;
  int lane = tid & 63;
  int w = tid >> 6;
  int wm = (w >> 1) << 6;   // wave's 64-row origin in 128-tile
  int wn = (w & 1) << 6;    // wave's 64-col origin
  long bm = (long)blockIdx.y * 128;
  long bn = (long)blockIdx.x * 128;

  f32x4 acc[4][4] = {};
  int qd = lane >> 4;   // k-chunk selector
  int fr = lane & 15;   // row (A) / col (B) within 16-tile

  // staging: LDS chunk q holds global (row r=q>>2, k-chunk c=(q&3)^(r&3))
  int r0s = tid >> 2,         c0s = (tid & 3) ^ (r0s & 3);
  int r1s = (tid + 256) >> 2, c1s = ((tid + 256) & 3) ^ (r1s & 3);

  for (int k0 = 0; k0 < p.K; k0 += 32) {
    long oa0 = (bm + r0s) * (long)p.lda + (k0 + c0s * 8);
    long oa1 = (bm + r1s) * (long)p.lda + (k0 + c1s * 8);
    long ob0 = (bn + r0s) * (long)p.ldb + (k0 + c0s * 8);
    long ob1 = (bn + r1s) * (long)p.ldb + (k0 + c1s * 8);
    bf16x8 a0 = *(const bf16x8*)(A + oa0);
    bf16x8 a1 = *(const bf16x8*)(A + oa1);
    bf16x8 b0 = *(const bf16x8*)(Bm + ob0);
    bf16x8 b1 = *(const bf16x8*)(Bm + ob1);
    bf16x8 al0, al1, bl0, bl1;
    if (SIN) {
      al0 = *(const bf16x8*)(Al + oa0); al1 = *(const bf16x8*)(Al + oa1);
      bl0 = *(const bf16x8*)(Bl + ob0); bl1 = *(const bf16x8*)(Bl + ob1);
    }
    __syncthreads();  // previous iteration's fragment reads complete
    *(bf16x8*)(lA + (size_t)tid * 8)         = a0;
    *(bf16x8*)(lA + (size_t)(tid + 256) * 8) = a1;
    *(bf16x8*)(lB + (size_t)tid * 8)         = b0;
    *(bf16x8*)(lB + (size_t)(tid + 256) * 8) = b1;
    if (SIN) {
      *(bf16x8*)(lAl + (size_t)tid * 8)         = al0;
      *(bf16x8*)(lAl + (size_t)(tid + 256) * 8) = al1;
      *(bf16x8*)(lBl + (size_t)tid * 8)         = bl0;
      *(bf16x8*)(lBl + (size_t)(tid + 256) * 8) = bl1;
    }
    __syncthreads();

    bf16x8 ah[4], bh[4], alv[4], blv[4];
#pragma unroll
    for (int i = 0; i < 4; ++i) {
      int m = wm + i * 16 + fr;
      size_t ia = ((size_t)m * 4 + (qd ^ (m & 3))) * 8;
      ah[i] = *(const bf16x8*)(lA + ia);
      if (SIN) alv[i] = *(const bf16x8*)(lAl + ia);
      int n = wn + i * 16 + fr;
      size_t ib = ((size_t)n * 4 + (qd ^ (n & 3))) * 8;
      bh[i] = *(const bf16x8*)(lB + ib);
      if (SIN) blv[i] = *(const bf16x8*)(lBl + ib);
    }
#pragma unroll
    for (int i = 0; i < 4; ++i)
#pragma unroll
      for (int j = 0; j < 4; ++j) {
        if (SIN) {
          acc[i][j] = __builtin_amdgcn_mfma_f32_16x16x32_bf16(alv[i], bh[j], acc[i][j], 0, 0, 0);
          acc[i][j] = __builtin_amdgcn_mfma_f32_16x16x32_bf16(ah[i], blv[j], acc[i][j], 0, 0, 0);
        }
        acc[i][j] = __builtin_amdgcn_mfma_f32_16x16x32_bf16(ah[i], bh[j], acc[i][j], 0, 0, 0);
      }
  }

  int rr0 = (lane >> 4) * 4;
#pragma unroll
  for (int i = 0; i < 4; ++i) {
#pragma unroll
    for (int j = 0; j < 4; ++j) {
#pragma unroll
      for (int r = 0; r < 4; ++r) {
        long row = bm + wm + i * 16 + rr0 + r;
        long col = bn + wn + j * 16 + fr;
        float v = acc[i][j][r];
        if (BIAS == 1) v += bias[col];
        if (BIAS == 2) v += bias[row];
        long idx = row * (long)p.ldc + col;
        if (SOUT) {
          bf16 h = (bf16)v;
          ((bf16*)C)[idx] = h;
          Cl[idx] = (bf16)(v - (float)h);
        } else {
          C[idx] = (OutT)v;
        }
      }
    }
  }
}

// one block per row of 2048 fp32 scores -> bf16 probabilities
__global__ __launch_bounds__(256) void softmax_kernel(const float* __restrict__ src,
                                                      bf16* __restrict__ dst, int n) {
  size_t row = blockIdx.x;
  const float* s = src + row * (size_t)n;
  bf16* d = dst + row * (size_t)n;
  int t = threadIdx.x;
  float4 v0 = ((const float4*)s)[t * 2];
  float4 v1 = ((const float4*)s)[t * 2 + 1];
  float e[8] = {v0.x, v0.y, v0.z, v0.w, v1.x, v1.y, v1.z, v1.w};
  float m = e[0];
#pragma unroll
  for (int i = 1; i < 8; ++i) m = fmaxf(m, e[i]);
#pragma unroll
  for (int off = 32; off >= 1; off >>= 1) m = fmaxf(m, __shfl_xor(m, off, 64));
  __shared__ float smm[4];
  __shared__ float ss[4];
  int w = t >> 6;
  if ((t & 63) == 0) smm[w] = m;
  __syncthreads();
  m = fmaxf(fmaxf(smm[0], smm[1]), fmaxf(smm[2], smm[3]));
  float sum = 0.f;
#pragma unroll
  for (int i = 0; i < 8; ++i) { e[i] = __expf(e[i] - m); sum += e[i]; }
#pragma unroll
  for (int off = 32; off >= 1; off >>= 1) sum += __shfl_xor(sum, off, 64);
  if ((t & 63) == 0) ss[w] = sum;
  __syncthreads();
  sum = ss[0] + ss[1] + ss[2] + ss[3];
  float inv = 1.0f / sum;
  bf16x8 ov;
#pragma unroll
  for (int i = 0; i < 8; ++i) ov[i] = (bf16)(e[i] * inv);
  *(bf16x8*)(d + t * 8) = ov;
}

extern "C" void kernel_launch(void* const* d_in, const int* in_sizes, int n_in,
                              void* d_out, int out_size, void* d_ws, size_t ws_size,
                              hipStream_t stream) {
  const float* x  = (const float*)d_in[0];
  const float* Wq = (const float*)d_in[1];
  const float* bq = (const float*)d_in[2];
  const float* Wk = (const float*)d_in[3];
  const float* bk = (const float*)d_in[4];
  const float* Wv = (const float*)d_in[5];
  const float* bv = (const float*)d_in[6];
  const float* Wo = (const float*)d_in[7];
  const float* bo = (const float*)d_in[8];
  float* out = (float*)d_out;  // OUTPUT IS FP32 (reference dtype)

  auto al = [](size_t v) { return (v + 255) & ~(size_t)255; };
  const size_t eX = (size_t)B_ * S_ * D_;       // 2M
  const size_t eW = (size_t)H_ * D_ * D_;       // 2M
  const size_t eSS = (size_t)S_ * S_;           // 4M

  size_t fixed = 2 * al(eX * 2)            // xhi,xlo
               + 2 * al(2 * eW * 2)        // wqk hi,lo
               + al(eW * 2)                // wv hi
               + al(eW * 2)                // wo hi
               + al((size_t)S_ * H_ * D_ * 2);  // catb
  // head-group ladder
  int GH = 1;
  for (int g = 8; g >= 1; g >>= 1) {
    size_t need = fixed + 2 * al(2ULL * g * S_ * D_ * 2) + al((size_t)g * D_ * S_ * 2)
                + al(eSS * 4) + al(eSS * 2);
    if (need <= ws_size) { GH = g; break; }
  }
  int GS = 1;
  for (int g = GH; g >= 1; g >>= 1) {
    size_t need = fixed + 2 * al(2ULL * GH * S_ * D_ * 2) + al((size_t)GH * D_ * S_ * 2)
                + al((size_t)g * eSS * 4) + al((size_t)g * eSS * 2);
    if (need <= ws_size) { GS = g; break; }
  }

  char* p0 = (char*)d_ws;
  size_t off = 0;
  bf16* xhi   = (bf16*)(p0 + off); off += al(eX * 2);
  bf16* xlo   = (bf16*)(p0 + off); off += al(eX * 2);
  bf16* wqkhi = (bf16*)(p0 + off); off += al(2 * eW * 2);   // [p*H+h][e][d]
  bf16* wqklo = (bf16*)(p0 + off); off += al(2 * eW * 2);
  bf16* wvhi  = (bf16*)(p0 + off); off += al(eW * 2);       // [h][e][d]
  bf16* wohi  = (bf16*)(p0 + off); off += al(eW * 2);       // [e][h*D+d]
  bf16* catb  = (bf16*)(p0 + off); off += al((size_t)S_ * H_ * D_ * 2);
  bf16* qkhi  = (bf16*)(p0 + off); off += al(2ULL * GH * S_ * D_ * 2);  // [p][gh][s][e]
  bf16* qklo  = (bf16*)(p0 + off); off += al(2ULL * GH * S_ * D_ * 2);
  bf16* vTb   = (bf16*)(p0 + off); off += al((size_t)GH * D_ * S_ * 2); // [gh][e][t]
  float* scores = (float*)(p0 + off); off += al((size_t)GS * eSS * 4);
  bf16* P     = (bf16*)(p0 + off);

  // ---- input prep: split x, transpose+split weights ----
  split_f32<<<dim3((eX + 255) / 256), 256, 0, stream>>>(x, xhi, xlo, (long)eX);
  dim3 tb(32, 8, 1);
  transpose_f32<<<dim3(16, 16, H_), tb, 0, stream>>>(Wq, wqkhi, wqklo, D_, D_);
  transpose_f32<<<dim3(16, 16, H_), tb, 0, stream>>>(Wk, wqkhi + eW, wqklo + eW, D_, D_);
  transpose_f32<<<dim3(16, 16, H_), tb, 0, stream>>>(Wv, wvhi, nullptr, D_, D_);
  transpose_f32<<<dim3(16, 128, 1), tb, 0, stream>>>(Wo, wohi, nullptr, H_ * D_, D_);

  for (int b = 0; b < B_; ++b) {
    const bf16* xbh = xhi + (size_t)b * S_ * D_;
    const bf16* xbl = xlo + (size_t)b * S_ * D_;
    for (int hg0 = 0; hg0 < H_; hg0 += GH) {
      {  // Q projection (split-in, split-out): qk[0][z][s][e]
        GemmArgs a{};
        a.A = xbh; a.Alo = xbl;
        a.Bm = wqkhi + (size_t)hg0 * D_ * D_; a.Blo = wqklo + (size_t)hg0 * D_ * D_;
        a.C = qkhi; a.Clo = qklo; a.bias = bq + (size_t)hg0 * D_;
        a.K = D_; a.lda = D_; a.ldb = D_; a.ldc = D_;
        a.sA = 0; a.sB = (size_t)D_ * D_; a.sC = (size_t)S_ * D_; a.sbias = D_;
        gemm_nt<bf16, 1, true, true><<<dim3(4, 16, GH), 256, 32768, stream>>>(a);
      }
      {  // K projection: qk[1][z][s][e]
        GemmArgs a{};
        a.A = xbh; a.Alo = xbl;
        a.Bm = wqkhi + (size_t)(H_ + hg0) * D_ * D_; a.Blo = wqklo + (size_t)(H_ + hg0) * D_ * D_;
        a.C = qkhi + (size_t)GH * S_ * D_; a.Clo = qklo + (size_t)GH * S_ * D_;
        a.bias = bk + (size_t)hg0 * D_;
        a.K = D_; a.lda = D_; a.ldb = D_; a.ldc = D_;
        a.sA = 0; a.sB = (size_t)D_ * D_; a.sC = (size_t)S_ * D_; a.sbias = D_;
        gemm_nt<bf16, 1, true, true><<<dim3(4, 16, GH), 256, 32768, stream>>>(a);
      }
      {  // V^T: vTb[z][e][t] = WvT[h]·x^T + bv  (plain bf16)
        GemmArgs a{};
        a.A = wvhi + (size_t)hg0 * D_ * D_; a.Bm = xbh;
        a.C = vTb; a.bias = bv + (size_t)hg0 * D_;
        a.K = D_; a.lda = D_; a.ldb = D_; a.ldc = S_;
        a.sA = (size_t)D_ * D_; a.sB = 0; a.sC = (size_t)D_ * S_; a.sbias = D_;
        gemm_nt<bf16, 2, false, false><<<dim3(16, 4, GH), 256, 16384, stream>>>(a);
      }
      for (int g0 = 0; g0 < GH; g0 += GS) {
        {  // scores = Q·K^T (split-in, fp32 out)
          GemmArgs a{};
          a.A = qkhi + (size_t)g0 * S_ * D_;          a.Alo = qklo + (size_t)g0 * S_ * D_;
          a.Bm = qkhi + (size_t)(GH + g0) * S_ * D_;  a.Blo = qklo + (size_t)(GH + g0) * S_ * D_;
          a.C = scores;
          a.K = D_; a.lda = D_; a.ldb = D_; a.ldc = S_;
          a.sA = (size_t)S_ * D_; a.sB = (size_t)S_ * D_; a.sC = eSS;
          gemm_nt<float, 0, true, false><<<dim3(16, 16, GS), 256, 32768, stream>>>(a);
        }
        softmax_kernel<<<dim3(GS * S_), 256, 0, stream>>>(scores, P, S_);
        {  // catb[s][(hg0+g0+z)*D+e] = P[z]·vT[g0+z]^T
          GemmArgs a{};
          a.A = P; a.Bm = vTb + (size_t)g0 * D_ * S_;
          a.C = catb + (size_t)(hg0 + g0) * D_;
          a.K = S_; a.lda = S_; a.ldb = S_; a.ldc = H_ * D_;
          a.sA = eSS; a.sB = (size_t)D_ * S_; a.sC = D_;
          gemm_nt<bf16, 0, false, false><<<dim3(4, 16, GS), 256, 16384, stream>>>(a);
        }
      }
    }
    {  // out[b] = catb·WoT^T + bo  -> FP32
      GemmArgs a{};
      a.A = catb; a.Bm = wohi;
      a.C = out + (size_t)b * S_ * D_; a.bias = bo;
      a.K = H_ * D_; a.lda = H_ * D_; a.ldb = H_ * D_; a.ldc = D_;
      a.sA = 0; a.sB = 0; a.sC = 0; a.sbias = 0;
      gemm_nt<float, 1, false, false><<<dim3(4, 16, 1), 256, 16384, stream>>>(a);
    }
  }
}